// Round 2
// baseline (1123.917 us; speedup 1.0000x reference)
//
#include <hip/hip_runtime.h>
#include <hip/hip_cooperative_groups.h>

namespace cg = cooperative_groups;

typedef _Float16 f16;
typedef _Float16 f16x8 __attribute__((ext_vector_type(8)));
typedef float f32x4 __attribute__((ext_vector_type(4)));

#define INV_R (1.0f / 40.0f)

// ---- workspace layout (bytes), total ~11.4 MB ----
#define OFF_HT   0u              // f16 [80][512]   h transposed (cols=n) for stage-1 B
#define OFF_B0   81920u          // f32 [64]        layer-0 bias (zeros ++ bf)
#define OFF_K0   82176u          // f16 [64][4320]  layer-0 fused kernel (conv|dense)
#define OFF_K1   635136u         // f16 [64][4160]
#define OFF_K2   1167616u
#define OFF_K3   1700096u
#define OFF_K4   2232576u        // f16 [16][4160]
#define OFF_TA   2365696u        // f16 [512][4320] t ping
#define OFF_TB   6789376u        // f16 [512][4160] t pong
#define OFF_OA   11049216u       // f32 [512][64]   out ping
#define OFF_OB   11180288u       // f32 [512][64]   out pong

#define PREP_TOTAL 1231936

__device__ __forceinline__ float feats0_val(int ch, int n, const float* v, const float* other) {
  if (ch == 0) return 1.0f;
  if (ch < 4) return v[n * 3 + (ch - 1)];
  return other[n * 62 + (ch - 4)];
}

__device__ void prep_body(const float* __restrict__ v, const float* __restrict__ other,
                          const float* __restrict__ kf, const float* __restrict__ Wf,
                          const float* __restrict__ bf,
                          const float* __restrict__ k1, const float* __restrict__ W1,
                          const float* __restrict__ k2, const float* __restrict__ W2,
                          const float* __restrict__ k3, const float* __restrict__ W3,
                          const float* __restrict__ k4, const float* __restrict__ W4,
                          char* __restrict__ ws) {
  for (int idx0 = blockIdx.x * 256 + threadIdx.x; idx0 < PREP_TOTAL; idx0 += 512 * 256) {
    int idx = idx0;
    if (idx < 40960) {                       // hT: feats0 transposed, rows 66..79 zero
      int i = idx >> 9, n = idx & 511;
      float val = (i < 66) ? feats0_val(i, n, v, other) : 0.0f;
      ((f16*)(ws + OFF_HT))[idx] = (f16)val;
      continue;
    }
    idx -= 40960;
    if (idx < 49152) {                       // tA dense-tail: feats0 per m, pad to 96
      int m = idx / 96, j = idx % 96;
      float val = (j < 66) ? feats0_val(j, m, v, other) : 0.0f;
      ((f16*)(ws + OFF_TA))[m * 4320 + 4224 + j] = (f16)val;
      continue;
    }
    idx -= 49152;
    if (idx < 276480) {                      // K0: rows 0..31 conv, rows 32..63 dense tail
      int o = idx / 4320, k = idx % 4320;
      float val = 0.0f;
      if (o < 32) { if (k < 4224) val = kf[o * 4224 + k]; }
      else if (k >= 4224 && k < 4290) val = Wf[(o - 32) * 66 + (k - 4224)];
      ((f16*)(ws + OFF_K0))[idx] = (f16)val;
      continue;
    }
    idx -= 276480;
    if (idx < 798720) {                      // K1..K3: conv flat ++ dense W tail
      int which = idx / 266240, e = idx % 266240;
      const float* kk = which == 0 ? k1 : (which == 1 ? k2 : k3);
      const float* WW = which == 0 ? W1 : (which == 1 ? W2 : W3);
      int o = e / 4160, k = e % 4160;
      float val = (k < 4096) ? kk[o * 4096 + k] : WW[o * 64 + (k - 4096)];
      ((f16*)(ws + OFF_K1 + (unsigned)which * 532480u))[e] = (f16)val;
      continue;
    }
    idx -= 798720;
    if (idx < 66560) {                       // K4 (6 rows + zero pad rows to 16)
      int o = idx / 4160, k = idx % 4160;
      float val = 0.0f;
      if (o < 6) val = (k < 4096) ? k4[o * 4096 + k] : W4[o * 64 + (k - 4096)];
      ((f16*)(ws + OFF_K4))[idx] = (f16)val;
      continue;
    }
    idx -= 66560;
    if (idx < 64) ((float*)(ws + OFF_B0))[idx] = (idx < 32) ? 0.0f : bf[idx - 32];
  }
}

// minimax atan on [-1,1], abs err ~2e-6
__device__ __forceinline__ float atan_poly(float t) {
  float t2 = t * t;
  float p = -0.0117212f;
  p = p * t2 + 0.05265332f;
  p = p * t2 - 0.11643287f;
  p = p * t2 + 0.19354346f;
  p = p * t2 - 0.33262347f;
  p = p * t2 + 0.99997726f;
  return t * p;
}

// grid_sample axis weights, size=4, align_corners=False, zero padding
__device__ __forceinline__ void axis_w(float g, int& i0c, int& i1c, float& w0, float& w1) {
  float c = 2.0f * g + 1.5f;
  float fl = floorf(c);
  float f = c - fl;
  int i0 = (int)fl;
  w0 = (i0 >= 0 && i0 <= 3) ? (1.0f - f) : 0.0f;   // tap at i0 (zero if out of range)
  w1 = (i0 >= -1 && i0 <= 2) ? f : 0.0f;           // tap at i0+1
  i0c = min(max(i0, 0), 3);
  i1c = min(max(i0 + 1, 0), 3);
}

// stage 1: per output point m (= blockIdx.x), build W[g][n] in LDS (scatter,
// collision-free by n), then t[g,i] = W @ hT^T via MFMA. Stores t as [m][i*64+g] fp16.
template<int CI, int ITILES, int KDIM>
__device__ void stage1_body(const float* __restrict__ p, const float* __restrict__ mask,
                            const f16* __restrict__ hT, f16* __restrict__ tout,
                            f16* __restrict__ Wlds) {
  int tid = threadIdx.x;
  int m = blockIdx.x;
  int4* wz4 = (int4*)Wlds;
  int4 zero4 = make_int4(0, 0, 0, 0);
  #pragma unroll
  for (int i = 0; i < 16; ++i) wz4[tid + i * 256] = zero4;
  float pmx = p[m * 3 + 0], pmy = p[m * 3 + 1], pmz = p[m * 3 + 2];
  __syncthreads();
  #pragma unroll
  for (int rep = 0; rep < 2; ++rep) {
    int n = rep * 256 + tid;
    float x = (p[n * 3 + 0] - pmx) * INV_R;
    float y = (p[n * 3 + 1] - pmy) * INV_R;
    float z = (p[n * 3 + 2] - pmz) * INV_R;
    float r2 = x * x + y * y + z * z;
    float q = 1.0f - r2;
    float att = (q > 0.0f) ? q * q * q * mask[n] : 0.0f;
    // map_polar_sqr
    float ax = fabsf(x), ay = fabsf(y);
    bool c1 = (x == 0.0f) && (y == 0.0f);
    bool c2 = (ay <= ax) && !c1;
    float r = sqrtf(x * x + y * y + 1e-9f);
    float num = c2 ? y : x;
    float den = c2 ? x : y;
    float a = atan_poly(num / den);        // NaN only when c1 (selected away)
    float s2 = copysignf(r, x), s3 = copysignf(r, y);
    const float C4PI = 1.2732395447351628f;
    float xs = c1 ? 0.0f : (c2 ? s2 : C4PI * s3 * a);
    float ys = c1 ? 0.0f : (c2 ? C4PI * s2 * a : s3);
    float zs = z;
    int iz0, iz1, iy0, iy1, ix0, ix1;
    float wz0, wz1, wy0, wy1, wx0, wx1;
    axis_w(zs, iz0, iz1, wz0, wz1);        // z -> kD (g high)
    axis_w(ys, iy0, iy1, wy0, wy1);        // y -> kH
    axis_w(xs, ix0, ix1, wx0, wx1);        // x -> kW (g low)
    wz0 *= att; wz1 *= att;
    int gz[2] = {iz0 * 16, iz1 * 16};
    int gy[2] = {iy0 * 4, iy1 * 4};
    int gx[2] = {ix0, ix1};
    float wzv[2] = {wz0, wz1}, wyv[2] = {wy0, wy1}, wxv[2] = {wx0, wx1};
    #pragma unroll
    for (int za = 0; za < 2; ++za)
      #pragma unroll
      for (int ya = 0; ya < 2; ++ya)
        #pragma unroll
        for (int xa = 0; xa < 2; ++xa) {
          float w = wzv[za] * wyv[ya] * wxv[xa];
          if (w != 0.0f) {   // skip zeros: LDS pre-zeroed, avoids clamped-index overwrite
            int g = gz[za] + gy[ya] + gx[xa];
            Wlds[g * 512 + (n ^ ((g & 7) << 3))] = (f16)w;
          }
        }
  }
  __syncthreads();
  // MFMA: wave w owns g-rows [16w,16w+16); tiles over i; K = n = 512
  int wave = tid >> 6, lane = tid & 63;
  int row = lane & 15, kgrp = lane >> 4;
  int grow = wave * 16 + row;
  f32x4 acc[ITILES];
  #pragma unroll
  for (int it = 0; it < ITILES; ++it) acc[it] = f32x4{0.f, 0.f, 0.f, 0.f};
  for (int k0 = 0; k0 < 512; k0 += 32) {
    int n0 = k0 + kgrp * 8;
    f16x8 afrag = *(f16x8*)&Wlds[grow * 512 + (n0 ^ ((grow & 7) << 3))];
    #pragma unroll
    for (int it = 0; it < ITILES; ++it) {
      int icol = it * 16 + row;
      f16x8 bfrag = *(const f16x8*)&hT[icol * 512 + n0];
      acc[it] = __builtin_amdgcn_mfma_f32_16x16x32_f16(afrag, bfrag, acc[it], 0, 0, 0);
    }
  }
  int g4 = wave * 16 + kgrp * 4;
  #pragma unroll
  for (int it = 0; it < ITILES; ++it) {
    int icol = it * 16 + row;
    if (icol < CI) {
      union { f16 h[4]; ushort4 u; } cv;
      #pragma unroll
      for (int r = 0; r < 4; ++r) cv.h[r] = (f16)acc[it][r];
      *(ushort4*)&tout[(size_t)m * KDIM + icol * 64 + g4] = cv.u;   // [m][i*64+g]
    }
  }
}

// stage 2: out[m,o] = t[m,:] . Kf[o,:] (conv + fused dense tail).
// 128 active blocks: mtile = b>>2 (16 m's), otile = b&3 (16 o's); 4 waves = K-split,
// LDS reduce; epilogue: +bias (+residual), write out32, emit next layer's fp16 operands.
template<int KDIM, bool RES, bool FINAL>
__device__ void stage2_body(const f16* __restrict__ t, const f16* __restrict__ Kf,
                            const float* __restrict__ bias, const float* __restrict__ res,
                            float* __restrict__ out32, f16* __restrict__ hT,
                            f16* __restrict__ tnext, float* __restrict__ dout,
                            float* __restrict__ red) {
  int b = blockIdx.x;
  if (b >= 128) return;
  int mtile = b >> 2, otile = b & 3;
  constexpr int KSTEPS = KDIM / 32;
  int tid = threadIdx.x;
  int kpart = tid >> 6, lane = tid & 63;
  int row = lane & 15, kgrp = lane >> 4;
  int mrow = mtile * 16 + row;
  int ocol = otile * 16 + row;
  f32x4 acc = {0.f, 0.f, 0.f, 0.f};
  for (int ks = kpart; ks < KSTEPS; ks += 4) {
    int k0 = ks * 32 + kgrp * 8;
    f16x8 afrag = *(const f16x8*)&t[(size_t)mrow * KDIM + k0];
    f16x8 bfrag = *(const f16x8*)&Kf[(size_t)ocol * KDIM + k0];
    acc = __builtin_amdgcn_mfma_f32_16x16x32_f16(afrag, bfrag, acc, 0, 0, 0);
  }
  if (kpart > 0) {
    #pragma unroll
    for (int r = 0; r < 4; ++r)
      red[(kpart - 1) * 256 + (kgrp * 4 + r) * 16 + row] = acc[r];
  }
  __syncthreads();
  if (kpart == 0) {
    #pragma unroll
    for (int kw = 0; kw < 3; ++kw)
      #pragma unroll
      for (int r = 0; r < 4; ++r)
        acc[r] += red[kw * 256 + (kgrp * 4 + r) * 16 + row];
    #pragma unroll
    for (int r = 0; r < 4; ++r) {
      int mm = mtile * 16 + kgrp * 4 + r;
      int oo = otile * 16 + row;
      if (FINAL) {
        if (oo < 6) dout[mm * 6 + oo] = acc[r] + bias[oo];
      } else {
        float val = acc[r] + bias[oo];
        if (RES) val += res[mm * 64 + oo];
        out32[mm * 64 + oo] = val;
        float h = fmaxf(val, 0.0f);
        hT[oo * 512 + mm] = (f16)h;                       // next stage-1 B operand
        tnext[(size_t)mm * 4160 + 4096 + oo] = (f16)h;    // next stage-2 dense tail
      }
    }
  }
}

__global__ __launch_bounds__(256, 2) void mega_kernel(
    const float* p, const float* v, const float* other, const float* mask,
    const float* kf, const float* Wf, const float* bf,
    const float* k1, const float* W1, const float* b1,
    const float* k2, const float* W2, const float* b2,
    const float* k3, const float* W3, const float* b3,
    const float* k4, const float* W4, const float* b4,
    float* dout, char* ws) {
  __shared__ int4 smem4[4096];             // 64 KB, aliased: stage1 W / stage2 reduce
  f16* Wlds = (f16*)smem4;
  float* red = (float*)smem4;
  cg::grid_group grid = cg::this_grid();

  f16* hT        = (f16*)(ws + OFF_HT);
  float* bias0   = (float*)(ws + OFF_B0);
  const f16* K0p = (const f16*)(ws + OFF_K0);
  const f16* K1p = (const f16*)(ws + OFF_K1);
  const f16* K2p = (const f16*)(ws + OFF_K2);
  const f16* K3p = (const f16*)(ws + OFF_K3);
  const f16* K4p = (const f16*)(ws + OFF_K4);
  f16* tA   = (f16*)(ws + OFF_TA);
  f16* tB   = (f16*)(ws + OFF_TB);
  float* outA = (float*)(ws + OFF_OA);
  float* outB = (float*)(ws + OFF_OB);

  prep_body(v, other, kf, Wf, bf, k1, W1, k2, W2, k3, W3, k4, W4, ws);
  __threadfence(); grid.sync();

  // layer 0 (Ci=66 -> concat(oc32, od32))
  stage1_body<66, 5, 4320>(p, mask, hT, tA, Wlds);
  __threadfence(); grid.sync();
  stage2_body<4320, false, false>(tA, K0p, bias0, nullptr, outA, hT, tB, nullptr, red);
  __threadfence(); grid.sync();
  // layer 1
  stage1_body<64, 4, 4160>(p, mask, hT, tB, Wlds);
  __threadfence(); grid.sync();
  stage2_body<4160, true, false>(tB, K1p, b1, outA, outB, hT, tA, nullptr, red);
  __threadfence(); grid.sync();
  // layer 2
  stage1_body<64, 4, 4160>(p, mask, hT, tA, Wlds);
  __threadfence(); grid.sync();
  stage2_body<4160, true, false>(tA, K2p, b2, outB, outA, hT, tB, nullptr, red);
  __threadfence(); grid.sync();
  // layer 3
  stage1_body<64, 4, 4160>(p, mask, hT, tB, Wlds);
  __threadfence(); grid.sync();
  stage2_body<4160, true, false>(tB, K3p, b3, outA, outB, hT, tA, nullptr, red);
  __threadfence(); grid.sync();
  // layer 4 (Co=6, no residual) -> d_out
  stage1_body<64, 4, 4160>(p, mask, hT, tA, Wlds);
  __threadfence(); grid.sync();
  stage2_body<4160, false, true>(tA, K4p, b4, nullptr, nullptr, nullptr, nullptr, dout, red);
}

extern "C" void kernel_launch(void* const* d_in, const int* in_sizes, int n_in,
                              void* d_out, int out_size, void* d_ws, size_t ws_size,
                              hipStream_t stream) {
  const float* p     = (const float*)d_in[0];
  const float* v     = (const float*)d_in[1];
  const float* other = (const float*)d_in[2];
  const float* mask  = (const float*)d_in[3];
  const float* kf    = (const float*)d_in[4];
  const float* Wf    = (const float*)d_in[5];
  const float* bf    = (const float*)d_in[6];
  const float* k1    = (const float*)d_in[7];
  const float* W1    = (const float*)d_in[8];
  const float* b1    = (const float*)d_in[9];
  const float* k2    = (const float*)d_in[10];
  const float* W2    = (const float*)d_in[11];
  const float* b2    = (const float*)d_in[12];
  const float* k3    = (const float*)d_in[13];
  const float* W3    = (const float*)d_in[14];
  const float* b3    = (const float*)d_in[15];
  const float* k4    = (const float*)d_in[16];
  const float* W4    = (const float*)d_in[17];
  const float* b4    = (const float*)d_in[18];
  float* dout = (float*)d_out;
  char* ws = (char*)d_ws;
  (void)in_sizes; (void)n_in; (void)out_size; (void)ws_size;

  void* args[] = {
    (void*)&p, (void*)&v, (void*)&other, (void*)&mask,
    (void*)&kf, (void*)&Wf, (void*)&bf,
    (void*)&k1, (void*)&W1, (void*)&b1,
    (void*)&k2, (void*)&W2, (void*)&b2,
    (void*)&k3, (void*)&W3, (void*)&b3,
    (void*)&k4, (void*)&W4, (void*)&b4,
    (void*)&dout, (void*)&ws
  };
  hipLaunchCooperativeKernel((const void*)mega_kernel, dim3(512), dim3(256),
                             args, 0, stream);
}

// Round 3
// 649.051 us; speedup vs baseline: 1.7316x; 1.7316x over previous
//
#include <hip/hip_runtime.h>

typedef _Float16 f16;
typedef _Float16 f16x8 __attribute__((ext_vector_type(8)));
typedef float f32x4 __attribute__((ext_vector_type(4)));

#define INV_R (1.0f / 40.0f)

// ---- workspace layout (bytes), total ~11.4 MB ----
#define OFF_HT   0u              // f16 [80][512]   h transposed (cols=n) for stage-1 B
#define OFF_B0   81920u          // f32 [64]        layer-0 bias (zeros ++ bf)
#define OFF_K0   82176u          // f16 [64][4320]  layer-0 fused kernel (conv|dense)
#define OFF_K1   635136u         // f16 [64][4160]
#define OFF_K2   1167616u
#define OFF_K3   1700096u
#define OFF_K4   2232576u        // f16 [16][4160]
#define OFF_TA   2365696u        // f16 [512][4320] t ping
#define OFF_TB   6789376u        // f16 [512][4160] t pong
#define OFF_OA   11049216u       // f32 [512][64]   out ping
#define OFF_OB   11180288u       // f32 [512][64]   out pong
#define OFF_CNT  11311360u       // u32 [16]        grid-barrier counters (memset 0 per replay)

#define PREP_TOTAL 1231936
#define NBLK 512u

// custom grid barrier: per-instance counter (never reused), agent-scope atomics,
// tight s_sleep poll. Requires all NBLK blocks co-resident (cooperative launch).
__device__ __forceinline__ void gridbar(unsigned* __restrict__ cnt, int i) {
  __syncthreads();                       // all block threads done with phase writes
  if (threadIdx.x == 0) {
    __threadfence();                     // release: flush this block's writes to agent scope
    __hip_atomic_fetch_add(&cnt[i], 1u, __ATOMIC_RELAXED, __HIP_MEMORY_SCOPE_AGENT);
    while (__hip_atomic_load(&cnt[i], __ATOMIC_RELAXED, __HIP_MEMORY_SCOPE_AGENT) < NBLK)
      __builtin_amdgcn_s_sleep(8);
    __threadfence();                     // acquire: invalidate stale cached lines
  }
  __syncthreads();
}

__device__ __forceinline__ float feats0_val(int ch, int n, const float* v, const float* other) {
  if (ch == 0) return 1.0f;
  if (ch < 4) return v[n * 3 + (ch - 1)];
  return other[n * 62 + (ch - 4)];
}

__device__ void prep_body(const float* __restrict__ v, const float* __restrict__ other,
                          const float* __restrict__ kf, const float* __restrict__ Wf,
                          const float* __restrict__ bf,
                          const float* __restrict__ k1, const float* __restrict__ W1,
                          const float* __restrict__ k2, const float* __restrict__ W2,
                          const float* __restrict__ k3, const float* __restrict__ W3,
                          const float* __restrict__ k4, const float* __restrict__ W4,
                          char* __restrict__ ws) {
  for (int idx0 = blockIdx.x * 256 + threadIdx.x; idx0 < PREP_TOTAL; idx0 += 512 * 256) {
    int idx = idx0;
    if (idx < 40960) {                       // hT: feats0 transposed, rows 66..79 zero
      int i = idx >> 9, n = idx & 511;
      float val = (i < 66) ? feats0_val(i, n, v, other) : 0.0f;
      ((f16*)(ws + OFF_HT))[idx] = (f16)val;
      continue;
    }
    idx -= 40960;
    if (idx < 49152) {                       // tA dense-tail: feats0 per m, pad to 96
      int m = idx / 96, j = idx % 96;
      float val = (j < 66) ? feats0_val(j, m, v, other) : 0.0f;
      ((f16*)(ws + OFF_TA))[m * 4320 + 4224 + j] = (f16)val;
      continue;
    }
    idx -= 49152;
    if (idx < 276480) {                      // K0: rows 0..31 conv, rows 32..63 dense tail
      int o = idx / 4320, k = idx % 4320;
      float val = 0.0f;
      if (o < 32) { if (k < 4224) val = kf[o * 4224 + k]; }
      else if (k >= 4224 && k < 4290) val = Wf[(o - 32) * 66 + (k - 4224)];
      ((f16*)(ws + OFF_K0))[idx] = (f16)val;
      continue;
    }
    idx -= 276480;
    if (idx < 798720) {                      // K1..K3: conv flat ++ dense W tail
      int which = idx / 266240, e = idx % 266240;
      const float* kk = which == 0 ? k1 : (which == 1 ? k2 : k3);
      const float* WW = which == 0 ? W1 : (which == 1 ? W2 : W3);
      int o = e / 4160, k = e % 4160;
      float val = (k < 4096) ? kk[o * 4096 + k] : WW[o * 64 + (k - 4096)];
      ((f16*)(ws + OFF_K1 + (unsigned)which * 532480u))[e] = (f16)val;
      continue;
    }
    idx -= 798720;
    if (idx < 66560) {                       // K4 (6 rows + zero pad rows to 16)
      int o = idx / 4160, k = idx % 4160;
      float val = 0.0f;
      if (o < 6) val = (k < 4096) ? k4[o * 4096 + k] : W4[o * 64 + (k - 4096)];
      ((f16*)(ws + OFF_K4))[idx] = (f16)val;
      continue;
    }
    idx -= 66560;
    if (idx < 64) ((float*)(ws + OFF_B0))[idx] = (idx < 32) ? 0.0f : bf[idx - 32];
  }
}

// minimax atan on [-1,1], abs err ~2e-6
__device__ __forceinline__ float atan_poly(float t) {
  float t2 = t * t;
  float p = -0.0117212f;
  p = p * t2 + 0.05265332f;
  p = p * t2 - 0.11643287f;
  p = p * t2 + 0.19354346f;
  p = p * t2 - 0.33262347f;
  p = p * t2 + 0.99997726f;
  return t * p;
}

// grid_sample axis weights, size=4, align_corners=False, zero padding
__device__ __forceinline__ void axis_w(float g, int& i0c, int& i1c, float& w0, float& w1) {
  float c = 2.0f * g + 1.5f;
  float fl = floorf(c);
  float f = c - fl;
  int i0 = (int)fl;
  w0 = (i0 >= 0 && i0 <= 3) ? (1.0f - f) : 0.0f;   // tap at i0 (zero if out of range)
  w1 = (i0 >= -1 && i0 <= 2) ? f : 0.0f;           // tap at i0+1
  i0c = min(max(i0, 0), 3);
  i1c = min(max(i0 + 1, 0), 3);
}

// stage 1: per output point m (= blockIdx.x), build W[g][n] in LDS (scatter,
// collision-free by n), then t[g,i] = W @ hT^T via MFMA. Stores t as [m][i*64+g] fp16.
template<int CI, int ITILES, int KDIM>
__device__ void stage1_body(const float* __restrict__ p, const float* __restrict__ mask,
                            const f16* __restrict__ hT, f16* __restrict__ tout,
                            f16* __restrict__ Wlds) {
  int tid = threadIdx.x;
  int m = blockIdx.x;
  int4* wz4 = (int4*)Wlds;
  int4 zero4 = make_int4(0, 0, 0, 0);
  #pragma unroll
  for (int i = 0; i < 16; ++i) wz4[tid + i * 256] = zero4;
  float pmx = p[m * 3 + 0], pmy = p[m * 3 + 1], pmz = p[m * 3 + 2];
  __syncthreads();
  #pragma unroll
  for (int rep = 0; rep < 2; ++rep) {
    int n = rep * 256 + tid;
    float x = (p[n * 3 + 0] - pmx) * INV_R;
    float y = (p[n * 3 + 1] - pmy) * INV_R;
    float z = (p[n * 3 + 2] - pmz) * INV_R;
    float r2 = x * x + y * y + z * z;
    float q = 1.0f - r2;
    float att = (q > 0.0f) ? q * q * q * mask[n] : 0.0f;
    // map_polar_sqr
    float ax = fabsf(x), ay = fabsf(y);
    bool c1 = (x == 0.0f) && (y == 0.0f);
    bool c2 = (ay <= ax) && !c1;
    float r = sqrtf(x * x + y * y + 1e-9f);
    float num = c2 ? y : x;
    float den = c2 ? x : y;
    float a = atan_poly(num / den);        // NaN only when c1 (selected away)
    float s2 = copysignf(r, x), s3 = copysignf(r, y);
    const float C4PI = 1.2732395447351628f;
    float xs = c1 ? 0.0f : (c2 ? s2 : C4PI * s3 * a);
    float ys = c1 ? 0.0f : (c2 ? C4PI * s2 * a : s3);
    float zs = z;
    int iz0, iz1, iy0, iy1, ix0, ix1;
    float wz0, wz1, wy0, wy1, wx0, wx1;
    axis_w(zs, iz0, iz1, wz0, wz1);        // z -> kD (g high)
    axis_w(ys, iy0, iy1, wy0, wy1);        // y -> kH
    axis_w(xs, ix0, ix1, wx0, wx1);        // x -> kW (g low)
    wz0 *= att; wz1 *= att;
    int gz[2] = {iz0 * 16, iz1 * 16};
    int gy[2] = {iy0 * 4, iy1 * 4};
    int gx[2] = {ix0, ix1};
    float wzv[2] = {wz0, wz1}, wyv[2] = {wy0, wy1}, wxv[2] = {wx0, wx1};
    #pragma unroll
    for (int za = 0; za < 2; ++za)
      #pragma unroll
      for (int ya = 0; ya < 2; ++ya)
        #pragma unroll
        for (int xa = 0; xa < 2; ++xa) {
          float w = wzv[za] * wyv[ya] * wxv[xa];
          if (w != 0.0f) {   // skip zeros: LDS pre-zeroed, avoids clamped-index overwrite
            int g = gz[za] + gy[ya] + gx[xa];
            Wlds[g * 512 + (n ^ ((g & 7) << 3))] = (f16)w;
          }
        }
  }
  __syncthreads();
  // MFMA: wave w owns g-rows [16w,16w+16); tiles over i; K = n = 512
  int wave = tid >> 6, lane = tid & 63;
  int row = lane & 15, kgrp = lane >> 4;
  int grow = wave * 16 + row;
  f32x4 acc[ITILES];
  #pragma unroll
  for (int it = 0; it < ITILES; ++it) acc[it] = f32x4{0.f, 0.f, 0.f, 0.f};
  for (int k0 = 0; k0 < 512; k0 += 32) {
    int n0 = k0 + kgrp * 8;
    f16x8 afrag = *(f16x8*)&Wlds[grow * 512 + (n0 ^ ((grow & 7) << 3))];
    #pragma unroll
    for (int it = 0; it < ITILES; ++it) {
      int icol = it * 16 + row;
      f16x8 bfrag = *(const f16x8*)&hT[icol * 512 + n0];
      acc[it] = __builtin_amdgcn_mfma_f32_16x16x32_f16(afrag, bfrag, acc[it], 0, 0, 0);
    }
  }
  int g4 = wave * 16 + kgrp * 4;
  #pragma unroll
  for (int it = 0; it < ITILES; ++it) {
    int icol = it * 16 + row;
    if (icol < CI) {
      union { f16 h[4]; ushort4 u; } cv;
      #pragma unroll
      for (int r = 0; r < 4; ++r) cv.h[r] = (f16)acc[it][r];
      *(ushort4*)&tout[(size_t)m * KDIM + icol * 64 + g4] = cv.u;   // [m][i*64+g]
    }
  }
}

// stage 2: out[m,o] = t[m,:] . Kf[o,:] (conv + fused dense tail).
// 128 active blocks: mtile = b>>2 (16 m's), otile = b&3 (16 o's); 4 waves = K-split,
// LDS reduce; epilogue: +bias (+residual), write out32, emit next layer's fp16 operands.
template<int KDIM, bool RES, bool FINAL>
__device__ void stage2_body(const f16* __restrict__ t, const f16* __restrict__ Kf,
                            const float* __restrict__ bias, const float* __restrict__ res,
                            float* __restrict__ out32, f16* __restrict__ hT,
                            f16* __restrict__ tnext, float* __restrict__ dout,
                            float* __restrict__ red) {
  int b = blockIdx.x;
  if (b >= 128) return;
  int mtile = b >> 2, otile = b & 3;
  constexpr int KSTEPS = KDIM / 32;
  int tid = threadIdx.x;
  int kpart = tid >> 6, lane = tid & 63;
  int row = lane & 15, kgrp = lane >> 4;
  int mrow = mtile * 16 + row;
  int ocol = otile * 16 + row;
  f32x4 acc = {0.f, 0.f, 0.f, 0.f};
  for (int ks = kpart; ks < KSTEPS; ks += 4) {
    int k0 = ks * 32 + kgrp * 8;
    f16x8 afrag = *(const f16x8*)&t[(size_t)mrow * KDIM + k0];
    f16x8 bfrag = *(const f16x8*)&Kf[(size_t)ocol * KDIM + k0];
    acc = __builtin_amdgcn_mfma_f32_16x16x32_f16(afrag, bfrag, acc, 0, 0, 0);
  }
  if (kpart > 0) {
    #pragma unroll
    for (int r = 0; r < 4; ++r)
      red[(kpart - 1) * 256 + (kgrp * 4 + r) * 16 + row] = acc[r];
  }
  __syncthreads();
  if (kpart == 0) {
    #pragma unroll
    for (int kw = 0; kw < 3; ++kw)
      #pragma unroll
      for (int r = 0; r < 4; ++r)
        acc[r] += red[kw * 256 + (kgrp * 4 + r) * 16 + row];
    #pragma unroll
    for (int r = 0; r < 4; ++r) {
      int mm = mtile * 16 + kgrp * 4 + r;
      int oo = otile * 16 + row;
      if (FINAL) {
        if (oo < 6) dout[mm * 6 + oo] = acc[r] + bias[oo];
      } else {
        float val = acc[r] + bias[oo];
        if (RES) val += res[mm * 64 + oo];
        out32[mm * 64 + oo] = val;
        float h = fmaxf(val, 0.0f);
        hT[oo * 512 + mm] = (f16)h;                       // next stage-1 B operand
        tnext[(size_t)mm * 4160 + 4096 + oo] = (f16)h;    // next stage-2 dense tail
      }
    }
  }
}

__global__ __launch_bounds__(256, 2) void mega_kernel(
    const float* p, const float* v, const float* other, const float* mask,
    const float* kf, const float* Wf, const float* bf,
    const float* k1, const float* W1, const float* b1,
    const float* k2, const float* W2, const float* b2,
    const float* k3, const float* W3, const float* b3,
    const float* k4, const float* W4, const float* b4,
    float* dout, char* ws) {
  __shared__ int4 smem4[4096];             // 64 KB, aliased: stage1 W / stage2 reduce
  f16* Wlds = (f16*)smem4;
  float* red = (float*)smem4;
  unsigned* cnt = (unsigned*)(ws + OFF_CNT);

  f16* hT        = (f16*)(ws + OFF_HT);
  float* bias0   = (float*)(ws + OFF_B0);
  const f16* K0p = (const f16*)(ws + OFF_K0);
  const f16* K1p = (const f16*)(ws + OFF_K1);
  const f16* K2p = (const f16*)(ws + OFF_K2);
  const f16* K3p = (const f16*)(ws + OFF_K3);
  const f16* K4p = (const f16*)(ws + OFF_K4);
  f16* tA   = (f16*)(ws + OFF_TA);
  f16* tB   = (f16*)(ws + OFF_TB);
  float* outA = (float*)(ws + OFF_OA);
  float* outB = (float*)(ws + OFF_OB);

  prep_body(v, other, kf, Wf, bf, k1, W1, k2, W2, k3, W3, k4, W4, ws);
  gridbar(cnt, 0);

  // layer 0 (Ci=66 -> concat(oc32, od32))
  stage1_body<66, 5, 4320>(p, mask, hT, tA, Wlds);
  gridbar(cnt, 1);
  stage2_body<4320, false, false>(tA, K0p, bias0, nullptr, outA, hT, tB, nullptr, red);
  gridbar(cnt, 2);
  // layer 1
  stage1_body<64, 4, 4160>(p, mask, hT, tB, Wlds);
  gridbar(cnt, 3);
  stage2_body<4160, true, false>(tB, K1p, b1, outA, outB, hT, tA, nullptr, red);
  gridbar(cnt, 4);
  // layer 2
  stage1_body<64, 4, 4160>(p, mask, hT, tA, Wlds);
  gridbar(cnt, 5);
  stage2_body<4160, true, false>(tA, K2p, b2, outB, outA, hT, tB, nullptr, red);
  gridbar(cnt, 6);
  // layer 3
  stage1_body<64, 4, 4160>(p, mask, hT, tB, Wlds);
  gridbar(cnt, 7);
  stage2_body<4160, true, false>(tB, K3p, b3, outA, outB, hT, tA, nullptr, red);
  gridbar(cnt, 8);
  // layer 4 (Co=6, no residual) -> d_out
  stage1_body<64, 4, 4160>(p, mask, hT, tA, Wlds);
  gridbar(cnt, 9);
  stage2_body<4160, false, true>(tA, K4p, b4, nullptr, nullptr, nullptr, nullptr, dout, red);
}

extern "C" void kernel_launch(void* const* d_in, const int* in_sizes, int n_in,
                              void* d_out, int out_size, void* d_ws, size_t ws_size,
                              hipStream_t stream) {
  const float* p     = (const float*)d_in[0];
  const float* v     = (const float*)d_in[1];
  const float* other = (const float*)d_in[2];
  const float* mask  = (const float*)d_in[3];
  const float* kf    = (const float*)d_in[4];
  const float* Wf    = (const float*)d_in[5];
  const float* bf    = (const float*)d_in[6];
  const float* k1    = (const float*)d_in[7];
  const float* W1    = (const float*)d_in[8];
  const float* b1    = (const float*)d_in[9];
  const float* k2    = (const float*)d_in[10];
  const float* W2    = (const float*)d_in[11];
  const float* b2    = (const float*)d_in[12];
  const float* k3    = (const float*)d_in[13];
  const float* W3    = (const float*)d_in[14];
  const float* b3    = (const float*)d_in[15];
  const float* k4    = (const float*)d_in[16];
  const float* W4    = (const float*)d_in[17];
  const float* b4    = (const float*)d_in[18];
  float* dout = (float*)d_out;
  char* ws = (char*)d_ws;
  (void)in_sizes; (void)n_in; (void)out_size; (void)ws_size;

  // zero the grid-barrier counters each call (ws is poisoned 0xAA before timing)
  hipMemsetAsync(ws + OFF_CNT, 0, 64, stream);

  void* args[] = {
    (void*)&p, (void*)&v, (void*)&other, (void*)&mask,
    (void*)&kf, (void*)&Wf, (void*)&bf,
    (void*)&k1, (void*)&W1, (void*)&b1,
    (void*)&k2, (void*)&W2, (void*)&b2,
    (void*)&k3, (void*)&W3, (void*)&b3,
    (void*)&k4, (void*)&W4, (void*)&b4,
    (void*)&dout, (void*)&ws
  };
  hipLaunchCooperativeKernel((const void*)mega_kernel, dim3(512), dim3(256),
                             args, 0, stream);
}

// Round 5
// 187.276 us; speedup vs baseline: 6.0014x; 3.4658x over previous
//
#include <hip/hip_runtime.h>

typedef _Float16 f16;
typedef _Float16 f16x8 __attribute__((ext_vector_type(8)));
typedef float f32x4 __attribute__((ext_vector_type(4)));

#define INV_R (1.0f / 40.0f)

// ---- workspace layout (bytes), total ~11.32 MB ----
#define OFF_HT   0u              // f16 [80][512]   h transposed (cols=n) for stage-1 B
#define OFF_B0   81920u          // f32 [64]        layer-0 bias (zeros ++ bf)
#define OFF_K0   82176u          // f16 [64][4320]  layer-0 fused kernel (conv|dense)
#define OFF_K1   635136u         // f16 [64][4160]
#define OFF_K2   1167616u
#define OFF_K3   1700096u
#define OFF_K4   2232576u        // f16 [16][4160]
#define OFF_TA   2365696u        // f16 [512][4320] t ping
#define OFF_TB   6789376u        // f16 [512][4160] t pong
#define OFF_OA   11049216u       // f32 [512][64]   out ping
#define OFF_OB   11180288u       // f32 [512][64]   out pong
#define OFF_BAR  11311360u       // u32 [576] hierarchical barrier state (memset 0 per call)

#define PREP_TOTAL 1231936
#define NBLK 512

// ============ hierarchical grid barrier ============
// Arrival: 8 per-XCD counters (separate lines, 64 adds each). Leaders (bid<8)
// aggregate into gcnt; block 0 releases grel; leaders fan out to 8 xrel flags.
// Max contention on any line: 64 pollers. Per-phase slots -> no reuse/reset races.
// Layout (u32 idx): xcnt[xcd*32+ph] 0..255 | xrel 256+xcd*32+ph | gcnt 512+ph | grel 544+ph
__device__ __forceinline__ unsigned bar_ld(unsigned* p) {
  return __hip_atomic_load(p, __ATOMIC_RELAXED, __HIP_MEMORY_SCOPE_AGENT);
}
__device__ void gridbar(unsigned* bar, int phase) {
  __syncthreads();
  if (threadIdx.x == 0) {
    int bid = blockIdx.x;
    int xcd = bid & 7;
    unsigned* xcnt = bar + xcd * 32 + phase;
    unsigned* xrel = bar + 256 + xcd * 32 + phase;
    unsigned* gcnt = bar + 512 + phase;
    unsigned* grel = bar + 544 + phase;
    __threadfence();                   // release: flush my block's writes
    __hip_atomic_fetch_add(xcnt, 1u, __ATOMIC_RELAXED, __HIP_MEMORY_SCOPE_AGENT);
    if (bid < 8) {                     // one leader per xcd-class
      while (bar_ld(xcnt) < (NBLK / 8)) __builtin_amdgcn_s_sleep(2);
      __hip_atomic_fetch_add(gcnt, 1u, __ATOMIC_RELAXED, __HIP_MEMORY_SCOPE_AGENT);
      if (bid == 0) {
        while (bar_ld(gcnt) < 8u) __builtin_amdgcn_s_sleep(2);
        __hip_atomic_store(grel, 1u, __ATOMIC_RELAXED, __HIP_MEMORY_SCOPE_AGENT);
      } else {
        while (bar_ld(grel) == 0u) __builtin_amdgcn_s_sleep(2);
      }
      __hip_atomic_store(xrel, 1u, __ATOMIC_RELAXED, __HIP_MEMORY_SCOPE_AGENT);
    } else {
      while (bar_ld(xrel) == 0u) __builtin_amdgcn_s_sleep(4);
    }
    __threadfence();                   // acquire: invalidate stale cached lines
  }
  __syncthreads();
}

// ================= shared math =================
__device__ __forceinline__ float feats0_val(int ch, int n, const float* v, const float* other) {
  if (ch == 0) return 1.0f;
  if (ch < 4) return v[n * 3 + (ch - 1)];
  return other[n * 62 + (ch - 4)];
}

__device__ void prep_body(const float* __restrict__ v, const float* __restrict__ other,
                          const float* __restrict__ kf, const float* __restrict__ Wf,
                          const float* __restrict__ bf,
                          const float* __restrict__ k1, const float* __restrict__ W1,
                          const float* __restrict__ k2, const float* __restrict__ W2,
                          const float* __restrict__ k3, const float* __restrict__ W3,
                          const float* __restrict__ k4, const float* __restrict__ W4,
                          char* __restrict__ ws) {
  for (int idx0 = blockIdx.x * 256 + threadIdx.x; idx0 < PREP_TOTAL; idx0 += 512 * 256) {
    int idx = idx0;
    if (idx < 40960) {                       // hT: feats0 transposed, rows 66..79 zero
      int i = idx >> 9, n = idx & 511;
      float val = (i < 66) ? feats0_val(i, n, v, other) : 0.0f;
      ((f16*)(ws + OFF_HT))[idx] = (f16)val;
      continue;
    }
    idx -= 40960;
    if (idx < 49152) {                       // tA dense-tail: feats0 per m, pad to 96
      int m = idx / 96, j = idx % 96;
      float val = (j < 66) ? feats0_val(j, m, v, other) : 0.0f;
      ((f16*)(ws + OFF_TA))[m * 4320 + 4224 + j] = (f16)val;
      continue;
    }
    idx -= 49152;
    if (idx < 276480) {                      // K0: rows 0..31 conv, rows 32..63 dense tail
      int o = idx / 4320, k = idx % 4320;
      float val = 0.0f;
      if (o < 32) { if (k < 4224) val = kf[o * 4224 + k]; }
      else if (k >= 4224 && k < 4290) val = Wf[(o - 32) * 66 + (k - 4224)];
      ((f16*)(ws + OFF_K0))[idx] = (f16)val;
      continue;
    }
    idx -= 276480;
    if (idx < 798720) {                      // K1..K3: conv flat ++ dense W tail
      int which = idx / 266240, e = idx % 266240;
      const float* kk = which == 0 ? k1 : (which == 1 ? k2 : k3);
      const float* WW = which == 0 ? W1 : (which == 1 ? W2 : W3);
      int o = e / 4160, k = e % 4160;
      float val = (k < 4096) ? kk[o * 4096 + k] : WW[o * 64 + (k - 4096)];
      ((f16*)(ws + OFF_K1 + (unsigned)which * 532480u))[e] = (f16)val;
      continue;
    }
    idx -= 798720;
    if (idx < 66560) {                       // K4 (6 rows + zero pad rows to 16)
      int o = idx / 4160, k = idx % 4160;
      float val = 0.0f;
      if (o < 6) val = (k < 4096) ? k4[o * 4096 + k] : W4[o * 64 + (k - 4096)];
      ((f16*)(ws + OFF_K4))[idx] = (f16)val;
      continue;
    }
    idx -= 66560;
    if (idx < 64) ((float*)(ws + OFF_B0))[idx] = (idx < 32) ? 0.0f : bf[idx - 32];
  }
}

// minimax atan on [-1,1], abs err ~2e-6
__device__ __forceinline__ float atan_poly(float t) {
  float t2 = t * t;
  float p = -0.0117212f;
  p = p * t2 + 0.05265332f;
  p = p * t2 - 0.11643287f;
  p = p * t2 + 0.19354346f;
  p = p * t2 - 0.33262347f;
  p = p * t2 + 0.99997726f;
  return t * p;
}

// grid_sample axis weights, size=4, align_corners=False, zero padding
__device__ __forceinline__ void axis_w(float g, int& i0c, int& i1c, float& w0, float& w1) {
  float c = 2.0f * g + 1.5f;
  float fl = floorf(c);
  float f = c - fl;
  int i0 = (int)fl;
  w0 = (i0 >= 0 && i0 <= 3) ? (1.0f - f) : 0.0f;   // tap at i0 (zero if out of range)
  w1 = (i0 >= -1 && i0 <= 2) ? f : 0.0f;           // tap at i0+1
  i0c = min(max(i0, 0), 3);
  i1c = min(max(i0 + 1, 0), 3);
}

// stage 1: per output point m (= blockIdx.x), build W[g][n] in LDS (scatter,
// collision-free by n), then t[g,i] = W @ hT^T via MFMA. Stores t as [m][i*64+g] fp16.
template<int CI, int ITILES, int KDIM>
__device__ void stage1_body(const float* __restrict__ p, const float* __restrict__ mask,
                            const f16* __restrict__ hT, f16* __restrict__ tout,
                            f16* __restrict__ Wlds) {
  int tid = threadIdx.x;
  int m = blockIdx.x;
  int4* wz4 = (int4*)Wlds;
  int4 zero4 = make_int4(0, 0, 0, 0);
  #pragma unroll
  for (int i = 0; i < 16; ++i) wz4[tid + i * 256] = zero4;
  float pmx = p[m * 3 + 0], pmy = p[m * 3 + 1], pmz = p[m * 3 + 2];
  __syncthreads();
  #pragma unroll
  for (int rep = 0; rep < 2; ++rep) {
    int n = rep * 256 + tid;
    float x = (p[n * 3 + 0] - pmx) * INV_R;
    float y = (p[n * 3 + 1] - pmy) * INV_R;
    float z = (p[n * 3 + 2] - pmz) * INV_R;
    float r2 = x * x + y * y + z * z;
    float q = 1.0f - r2;
    float att = (q > 0.0f) ? q * q * q * mask[n] : 0.0f;
    bool c1 = (x == 0.0f) && (y == 0.0f);
    bool c2 = (fabsf(y) <= fabsf(x)) && !c1;
    float r = sqrtf(x * x + y * y + 1e-9f);
    float num = c2 ? y : x;
    float den = c2 ? x : y;
    float a = atan_poly(num / den);
    float s2 = copysignf(r, x), s3 = copysignf(r, y);
    const float C4PI = 1.2732395447351628f;
    float xs = c1 ? 0.0f : (c2 ? s2 : C4PI * s3 * a);
    float ys = c1 ? 0.0f : (c2 ? C4PI * s2 * a : s3);
    float zs = z;
    int iz0, iz1, iy0, iy1, ix0, ix1;
    float wz0, wz1, wy0, wy1, wx0, wx1;
    axis_w(zs, iz0, iz1, wz0, wz1);
    axis_w(ys, iy0, iy1, wy0, wy1);
    axis_w(xs, ix0, ix1, wx0, wx1);
    wz0 *= att; wz1 *= att;
    int gz[2] = {iz0 * 16, iz1 * 16};
    int gy[2] = {iy0 * 4, iy1 * 4};
    int gx[2] = {ix0, ix1};
    float wzv[2] = {wz0, wz1}, wyv[2] = {wy0, wy1}, wxv[2] = {wx0, wx1};
    #pragma unroll
    for (int za = 0; za < 2; ++za)
      #pragma unroll
      for (int ya = 0; ya < 2; ++ya)
        #pragma unroll
        for (int xa = 0; xa < 2; ++xa) {
          float w = wzv[za] * wyv[ya] * wxv[xa];
          if (w != 0.0f) {
            int g = gz[za] + gy[ya] + gx[xa];
            Wlds[g * 512 + (n ^ ((g & 7) << 3))] = (f16)w;
          }
        }
  }
  __syncthreads();
  int wave = tid >> 6, lane = tid & 63;
  int row = lane & 15, kgrp = lane >> 4;
  int grow = wave * 16 + row;
  f32x4 acc[ITILES];
  #pragma unroll
  for (int it = 0; it < ITILES; ++it) acc[it] = f32x4{0.f, 0.f, 0.f, 0.f};
  for (int k0 = 0; k0 < 512; k0 += 32) {
    int n0 = k0 + kgrp * 8;
    f16x8 afrag = *(f16x8*)&Wlds[grow * 512 + (n0 ^ ((grow & 7) << 3))];
    #pragma unroll
    for (int it = 0; it < ITILES; ++it) {
      int icol = it * 16 + row;
      f16x8 bfrag = *(const f16x8*)&hT[icol * 512 + n0];
      acc[it] = __builtin_amdgcn_mfma_f32_16x16x32_f16(afrag, bfrag, acc[it], 0, 0, 0);
    }
  }
  int g4 = wave * 16 + kgrp * 4;
  #pragma unroll
  for (int it = 0; it < ITILES; ++it) {
    int icol = it * 16 + row;
    if (icol < CI) {
      union { f16 h[4]; ushort4 u; } cv;
      #pragma unroll
      for (int r = 0; r < 4; ++r) cv.h[r] = (f16)acc[it][r];
      *(ushort4*)&tout[(size_t)m * KDIM + icol * 64 + g4] = cv.u;   // [m][i*64+g]
    }
  }
}

// stage 2: out[m,o] = t[m,:] . Kf[o,:] (conv + fused dense tail).
// 128 active blocks: mtile = b>>2, otile = b&3; 4 waves = K-split, LDS reduce;
// epilogue: +bias (+residual), write out32, emit next layer's fp16 operands.
template<int KDIM, bool RES, bool FINAL>
__device__ void stage2_body(const f16* __restrict__ t, const f16* __restrict__ Kf,
                            const float* __restrict__ bias, const float* __restrict__ res,
                            float* __restrict__ out32, f16* __restrict__ hT,
                            f16* __restrict__ tnext, float* __restrict__ dout,
                            float* __restrict__ red) {
  int b = blockIdx.x;
  if (b >= 128) return;
  int mtile = b >> 2, otile = b & 3;
  constexpr int KSTEPS = KDIM / 32;
  int tid = threadIdx.x;
  int kpart = tid >> 6, lane = tid & 63;
  int row = lane & 15, kgrp = lane >> 4;
  int mrow = mtile * 16 + row;
  int ocol = otile * 16 + row;
  f32x4 acc = {0.f, 0.f, 0.f, 0.f};
  for (int ks = kpart; ks < KSTEPS; ks += 4) {
    int k0 = ks * 32 + kgrp * 8;
    f16x8 afrag = *(const f16x8*)&t[(size_t)mrow * KDIM + k0];
    f16x8 bfrag = *(const f16x8*)&Kf[(size_t)ocol * KDIM + k0];
    acc = __builtin_amdgcn_mfma_f32_16x16x32_f16(afrag, bfrag, acc, 0, 0, 0);
  }
  if (kpart > 0) {
    #pragma unroll
    for (int r = 0; r < 4; ++r)
      red[(kpart - 1) * 256 + (kgrp * 4 + r) * 16 + row] = acc[r];
  }
  __syncthreads();
  if (kpart == 0) {
    #pragma unroll
    for (int kw = 0; kw < 3; ++kw)
      #pragma unroll
      for (int r = 0; r < 4; ++r)
        acc[r] += red[kw * 256 + (kgrp * 4 + r) * 16 + row];
    #pragma unroll
    for (int r = 0; r < 4; ++r) {
      int mm = mtile * 16 + kgrp * 4 + r;
      int oo = otile * 16 + row;
      if (FINAL) {
        if (oo < 6) dout[mm * 6 + oo] = acc[r] + bias[oo];
      } else {
        float val = acc[r] + bias[oo];
        if (RES) val += res[mm * 64 + oo];
        out32[mm * 64 + oo] = val;
        float h = fmaxf(val, 0.0f);
        hT[oo * 512 + mm] = (f16)h;                       // next stage-1 B operand
        tnext[(size_t)mm * 4160 + 4096 + oo] = (f16)h;    // next stage-2 dense tail
      }
    }
  }
}

// ================= cooperative mega-kernel =================
__global__ __launch_bounds__(256, 2) void mega_kernel(
    const float* p, const float* v, const float* other, const float* mask,
    const float* kf, const float* Wf, const float* bf,
    const float* k1, const float* W1, const float* b1,
    const float* k2, const float* W2, const float* b2,
    const float* k3, const float* W3, const float* b3,
    const float* k4, const float* W4, const float* b4,
    float* dout, char* ws) {
  __shared__ int4 smem4[4096];             // 64 KB: stage1 W / stage2 reduce
  f16* Wlds = (f16*)smem4;
  float* red = (float*)smem4;
  unsigned* bar = (unsigned*)(ws + OFF_BAR);

  f16* hT        = (f16*)(ws + OFF_HT);
  float* bias0   = (float*)(ws + OFF_B0);
  const f16* K0p = (const f16*)(ws + OFF_K0);
  const f16* K1p = (const f16*)(ws + OFF_K1);
  const f16* K2p = (const f16*)(ws + OFF_K2);
  const f16* K3p = (const f16*)(ws + OFF_K3);
  const f16* K4p = (const f16*)(ws + OFF_K4);
  f16* tA   = (f16*)(ws + OFF_TA);
  f16* tB   = (f16*)(ws + OFF_TB);
  float* outA = (float*)(ws + OFF_OA);
  float* outB = (float*)(ws + OFF_OB);

  prep_body(v, other, kf, Wf, bf, k1, W1, k2, W2, k3, W3, k4, W4, ws);
  gridbar(bar, 0);
  // layer 0
  stage1_body<66, 5, 4320>(p, mask, hT, tA, Wlds);
  gridbar(bar, 1);
  stage2_body<4320, false, false>(tA, K0p, bias0, nullptr, outA, hT, tB, nullptr, red);
  gridbar(bar, 2);
  // layer 1
  stage1_body<64, 4, 4160>(p, mask, hT, tB, Wlds);
  gridbar(bar, 3);
  stage2_body<4160, true, false>(tB, K1p, b1, outA, outB, hT, tA, nullptr, red);
  gridbar(bar, 4);
  // layer 2
  stage1_body<64, 4, 4160>(p, mask, hT, tA, Wlds);
  gridbar(bar, 5);
  stage2_body<4160, true, false>(tA, K2p, b2, outB, outA, hT, tB, nullptr, red);
  gridbar(bar, 6);
  // layer 3
  stage1_body<64, 4, 4160>(p, mask, hT, tB, Wlds);
  gridbar(bar, 7);
  stage2_body<4160, true, false>(tB, K3p, b3, outA, outB, hT, tA, nullptr, red);
  gridbar(bar, 8);
  // layer 4 -> d_out
  stage1_body<64, 4, 4160>(p, mask, hT, tA, Wlds);
  gridbar(bar, 9);
  stage2_body<4160, false, true>(tA, K4p, b4, nullptr, nullptr, nullptr, nullptr, dout, red);
}

// ================= fallback wrappers (same proven bodies, 11 launches) =================
__global__ void prep_kernel_g(const float* v, const float* other,
                              const float* kf, const float* Wf, const float* bf,
                              const float* k1, const float* W1,
                              const float* k2, const float* W2,
                              const float* k3, const float* W3,
                              const float* k4, const float* W4, char* ws) {
  prep_body(v, other, kf, Wf, bf, k1, W1, k2, W2, k3, W3, k4, W4, ws);
}

template<int CI, int ITILES, int KDIM>
__global__ __launch_bounds__(256) void stage1_kernel_g(const float* p, const float* mask,
                                                       const f16* hT, f16* tout) {
  __shared__ int4 smem4[4096];
  stage1_body<CI, ITILES, KDIM>(p, mask, hT, tout, (f16*)smem4);
}

template<int KDIM, bool RES, bool FINAL>
__global__ __launch_bounds__(256) void stage2_kernel_g(const f16* t, const f16* Kf,
                                                       const float* bias, const float* res,
                                                       float* out32, f16* hT, f16* tnext,
                                                       float* dout) {
  __shared__ float red[3 * 256];
  stage2_body<KDIM, RES, FINAL>(t, Kf, bias, res, out32, hT, tnext, dout, red);
}

extern "C" void kernel_launch(void* const* d_in, const int* in_sizes, int n_in,
                              void* d_out, int out_size, void* d_ws, size_t ws_size,
                              hipStream_t stream) {
  const float* p     = (const float*)d_in[0];
  const float* v     = (const float*)d_in[1];
  const float* other = (const float*)d_in[2];
  const float* mask  = (const float*)d_in[3];
  const float* kf    = (const float*)d_in[4];
  const float* Wf    = (const float*)d_in[5];
  const float* bf    = (const float*)d_in[6];
  const float* k1    = (const float*)d_in[7];
  const float* W1    = (const float*)d_in[8];
  const float* b1    = (const float*)d_in[9];
  const float* k2    = (const float*)d_in[10];
  const float* W2    = (const float*)d_in[11];
  const float* b2    = (const float*)d_in[12];
  const float* k3    = (const float*)d_in[13];
  const float* W3    = (const float*)d_in[14];
  const float* b3    = (const float*)d_in[15];
  const float* k4    = (const float*)d_in[16];
  const float* W4    = (const float*)d_in[17];
  const float* b4    = (const float*)d_in[18];
  float* dout = (float*)d_out;
  char* ws = (char*)d_ws;
  (void)in_sizes; (void)n_in; (void)out_size; (void)ws_size;

  f16* hT        = (f16*)(ws + OFF_HT);
  float* bias0   = (float*)(ws + OFF_B0);
  const f16* K0p = (const f16*)(ws + OFF_K0);
  const f16* K1p = (const f16*)(ws + OFF_K1);
  const f16* K2p = (const f16*)(ws + OFF_K2);
  const f16* K3p = (const f16*)(ws + OFF_K3);
  const f16* K4p = (const f16*)(ws + OFF_K4);
  f16* tA   = (f16*)(ws + OFF_TA);
  f16* tB   = (f16*)(ws + OFF_TB);
  float* outA = (float*)(ws + OFF_OA);
  float* outB = (float*)(ws + OFF_OB);

  // ---- try cooperative mega-kernel path ----
  int maxb = 0;
  hipError_t e1 = hipOccupancyMaxActiveBlocksPerMultiprocessor(
      &maxb, (const void*)mega_kernel, 256, 0);
  if (e1 == hipSuccess && maxb >= 2) {
    hipMemsetAsync(ws + OFF_BAR, 0, 2304, stream);   // zero barrier slots each call
    void* args[] = {
      (void*)&p, (void*)&v, (void*)&other, (void*)&mask,
      (void*)&kf, (void*)&Wf, (void*)&bf,
      (void*)&k1, (void*)&W1, (void*)&b1,
      (void*)&k2, (void*)&W2, (void*)&b2,
      (void*)&k3, (void*)&W3, (void*)&b3,
      (void*)&k4, (void*)&W4, (void*)&b4,
      (void*)&dout, (void*)&ws
    };
    hipError_t e2 = hipLaunchCooperativeKernel((const void*)mega_kernel, dim3(NBLK),
                                               dim3(256), args, 0, stream);
    if (e2 == hipSuccess) return;
  }

  // ---- fallback: 11 plain launches of the same bodies (proven path) ----
  prep_kernel_g<<<512, 256, 0, stream>>>(v, other, kf, Wf, bf, k1, W1, k2, W2,
                                         k3, W3, k4, W4, ws);
  stage1_kernel_g<66, 5, 4320><<<512, 256, 0, stream>>>(p, mask, hT, tA);
  stage2_kernel_g<4320, false, false><<<128, 256, 0, stream>>>(tA, K0p, bias0, nullptr,
                                                               outA, hT, tB, nullptr);
  stage1_kernel_g<64, 4, 4160><<<512, 256, 0, stream>>>(p, mask, hT, tB);
  stage2_kernel_g<4160, true, false><<<128, 256, 0, stream>>>(tB, K1p, b1, outA,
                                                              outB, hT, tA, nullptr);
  stage1_kernel_g<64, 4, 4160><<<512, 256, 0, stream>>>(p, mask, hT, tA);
  stage2_kernel_g<4160, true, false><<<128, 256, 0, stream>>>(tA, K2p, b2, outB,
                                                              outA, hT, tB, nullptr);
  stage1_kernel_g<64, 4, 4160><<<512, 256, 0, stream>>>(p, mask, hT, tB);
  stage2_kernel_g<4160, true, false><<<128, 256, 0, stream>>>(tB, K3p, b3, outA,
                                                              outB, hT, tA, nullptr);
  stage1_kernel_g<64, 4, 4160><<<512, 256, 0, stream>>>(p, mask, hT, tA);
  stage2_kernel_g<4160, false, true><<<128, 256, 0, stream>>>(tA, K4p, b4, nullptr,
                                                              nullptr, nullptr, nullptr, dout);
}